// Round 22
// baseline (478.415 us; speedup 1.0000x reference)
//
#include <hip/hip_runtime.h>
#include <hip/hip_bf16.h>
#include <cstdint>

// Problem constants (match setup_inputs)
constexpr int B  = 2;
constexpr int L  = 2048;
constexpr int S  = 2048;
constexpr int DM = 1024;
constexpr int H  = 16;
constexpr int R  = 32;     // rank
constexpr int DH = 64;     // head dim
constexpr int TOPK = 32;
constexpr int SELCAP = 36;
constexpr float SCALE = 0.17677669529663687f; // 1/sqrt(32)

// MEASURED (R4-R21): VGPR cap = LDS-implied occupancy; LICM -> opaque-zero
// asm. R21: SW-pipelining neutral (compiler re-serializes; TLP covers).
// R22: float-domain selection (monotone bijection -> convert only lane-max +
// <=2 candidates, not all 32) and fragment-ordered W splits (B-operand
// direct from L2, no LDS staging in mfma GEMMs). Both bit-identical.

using short8 = __attribute__((ext_vector_type(8))) short;
using f32x4  = __attribute__((ext_vector_type(4))) float;

__device__ __forceinline__ unsigned short bf16_rne(float x) {
    unsigned int u = __float_as_uint(x);
    unsigned int r = u + 0x7FFFu + ((u >> 16) & 1u);
    return (unsigned short)(r >> 16);
}
__device__ __forceinline__ float bf16_up(unsigned short h) {
    return __uint_as_float((unsigned int)h << 16);
}
__device__ __forceinline__ unsigned int to_sortable(float f) {
    unsigned int bb  = __float_as_uint(f);
    unsigned int sgn = (unsigned int)(((int)bb) >> 31);
    return bb ^ (sgn | 0x80000000u);
}
__device__ __forceinline__ float inv_sortable(unsigned int uu) {
    unsigned int sg2 = (unsigned int)(((int)uu) >> 31);
    return __uint_as_float(uu ^ (0x80000000u | ~sg2));
}

// ---------------------------------------------------------------------------
// Merged Q/K projection. z=0: Q -> fp32 Qp (pre-scaled). z=1: K -> 3-term
// bf16 splits in MFMA-fragment order (R17-proven).
// ---------------------------------------------------------------------------
__global__ __launch_bounds__(256, 2)
void qk_proj(const float* __restrict__ Aq, const float* __restrict__ Wq_,
             const float* __restrict__ bq_, float* __restrict__ Qp,
             const float* __restrict__ Ak, const float* __restrict__ Wk_,
             const float* __restrict__ bk_, unsigned short* __restrict__ Kf,
             int M, int N, int K)
{
    const int z = blockIdx.z;
    const float* A    = z ? Ak  : Aq;
    const float* W    = z ? Wk_ : Wq_;
    const float* bias = z ? bk_ : bq_;

    __shared__ float As[16][136];
    __shared__ float Ws[16][132];

    const int t  = threadIdx.x;
    const int tx = t & 15;
    const int ty = t >> 4;
    const int m0 = blockIdx.y * 128;
    const int n0 = blockIdx.x * 128;

    float acc[8][8];
#pragma unroll
    for (int i = 0; i < 8; ++i)
#pragma unroll
        for (int j = 0; j < 8; ++j) acc[i][j] = 0.f;

    for (int kb = 0; kb < K; kb += 16) {
        __syncthreads();
#pragma unroll
        for (int it = 0; it < 2; ++it) {
            int f4  = t + it * 256;
            int row = f4 >> 2;
            int cg  = (f4 & 3) * 4;
            float4 av = *(const float4*)&A[(size_t)(m0 + row) * K + kb + cg];
            As[cg + 0][row] = av.x;
            As[cg + 1][row] = av.y;
            As[cg + 2][row] = av.z;
            As[cg + 3][row] = av.w;
        }
#pragma unroll
        for (int it = 0; it < 2; ++it) {
            int f4 = t + it * 256;
            int kk = f4 >> 5;
            int cb = (f4 & 31) * 4;
            *(float4*)&Ws[kk][cb] = *(const float4*)&W[(size_t)(kb + kk) * N + n0 + cb];
        }
        __syncthreads();
#pragma unroll
        for (int kk = 0; kk < 16; ++kk) {
            float4 a0 = *(const float4*)&As[kk][ty * 8];
            float4 a1 = *(const float4*)&As[kk][ty * 8 + 4];
            float4 w0 = *(const float4*)&Ws[kk][tx * 8];
            float4 w1 = *(const float4*)&Ws[kk][tx * 8 + 4];
            float a[8] = {a0.x, a0.y, a0.z, a0.w, a1.x, a1.y, a1.z, a1.w};
            float w[8] = {w0.x, w0.y, w0.z, w0.w, w1.x, w1.y, w1.z, w1.w};
#pragma unroll
            for (int i = 0; i < 8; ++i)
#pragma unroll
                for (int j = 0; j < 8; ++j)
                    acc[i][j] = fmaf(a[i], w[j], acc[i][j]);
        }
    }

    float4 b0 = *(const float4*)&bias[n0 + tx * 8];
    float4 b1 = *(const float4*)&bias[n0 + tx * 8 + 4];

    if (z == 0) {
#pragma unroll
        for (int i = 0; i < 8; ++i) {
            float4 o0 = make_float4((acc[i][0] + b0.x) * SCALE, (acc[i][1] + b0.y) * SCALE,
                                    (acc[i][2] + b0.z) * SCALE, (acc[i][3] + b0.w) * SCALE);
            float4 o1 = make_float4((acc[i][4] + b1.x) * SCALE, (acc[i][5] + b1.y) * SCALE,
                                    (acc[i][6] + b1.z) * SCALE, (acc[i][7] + b1.w) * SCALE);
            size_t off = (size_t)(m0 + ty * 8 + i) * N + n0 + tx * 8;
            *(float4*)&Qp[off]     = o0;
            *(float4*)&Qp[off + 4] = o1;
        }
    } else {
        float bb[8] = {b0.x, b0.y, b0.z, b0.w, b1.x, b1.y, b1.z, b1.w};
        const int h2 = (n0 + tx * 8) >> 5;
        const int l4 = ((n0 + tx * 8) & 31) >> 3;
#pragma unroll
        for (int i = 0; i < 8; ++i) {
            unsigned short hh[8], mm[8], ll[8];
#pragma unroll
            for (int j = 0; j < 8; ++j) {
                float x = acc[i][j] + bb[j];
                hh[j] = bf16_rne(x);
                float xr = x - bf16_up(hh[j]);
                mm[j] = bf16_rne(xr);
                ll[j] = bf16_rne(xr - bf16_up(mm[j]));
            }
            const int grow = m0 + ty * 8 + i;
            const int bat  = grow >> 11;
            const int key  = grow & 2047;
            const int T    = key >> 4;
            const int l15  = key & 15;
            const size_t base = (((size_t)(bat * H + h2) * 128 + T) * 1536)
                              + (size_t)(l4 * 16 + l15) * 8;
            ushort4 h0v = {hh[0], hh[1], hh[2], hh[3]}, h1v = {hh[4], hh[5], hh[6], hh[7]};
            ushort4 m0v = {mm[0], mm[1], mm[2], mm[3]}, m1v = {mm[4], mm[5], mm[6], mm[7]};
            ushort4 l0v = {ll[0], ll[1], ll[2], ll[3]}, l1v = {ll[4], ll[5], ll[6], ll[7]};
            *(ushort4*)&Kf[base]            = h0v;
            *(ushort4*)&Kf[base + 4]        = h1v;
            *(ushort4*)&Kf[base + 512]      = m0v;
            *(ushort4*)&Kf[base + 512 + 4]  = m1v;
            *(ushort4*)&Kf[base + 1024]     = l0v;
            *(ushort4*)&Kf[base + 1024 + 4] = l1v;
        }
    }
}

// ---------------------------------------------------------------------------
// Dual transpose + split, writing FRAGMENT-ORDERED planes:
// element (n,k) -> [(n>>4)*32 + (k>>5)]*512 + (((k>>3)&3)*16 + (n&15))*8 + (k&7)
// Same values/rounding as before -> GEMM consumes identical fragments.
// ---------------------------------------------------------------------------
__global__ __launch_bounds__(256)
void transpose_split_dual(const float* __restrict__ Wv_, unsigned short* __restrict__ VhT,
                          unsigned short* __restrict__ VlT,
                          const float* __restrict__ Wo_, unsigned short* __restrict__ OhT,
                          unsigned short* __restrict__ OlT, int N, int K)
{
    const int z = blockIdx.z;
    const float* W = z ? Wo_ : Wv_;
    unsigned short* Th = z ? OhT : VhT;
    unsigned short* Tl = z ? OlT : VlT;

    __shared__ float tile[32][33];
    const int n0 = blockIdx.x * 32;
    const int k0 = blockIdx.y * 32;
    const int tx = threadIdx.x & 31;
    const int ty = threadIdx.x >> 5;

#pragma unroll
    for (int i = ty; i < 32; i += 8)
        tile[i][tx] = W[(size_t)(k0 + i) * N + n0 + tx];
    __syncthreads();

    const int kk  = k0 + tx;
    const int c32 = kk >> 5;
    const int l4v = (kk >> 3) & 3;
    const int el  = kk & 7;
#pragma unroll
    for (int i = ty; i < 32; i += 8) {
        float x = tile[tx][i];                 // = W[k0+tx][n0+i]
        unsigned short h = bf16_rne(x);
        float hf = bf16_up(h);
        unsigned short l = bf16_rne(x - hf);
        const int n   = n0 + i;
        const size_t fo = ((size_t)(n >> 4) * 32 + c32) * 512
                        + (size_t)(l4v * 16 + (n & 15)) * 8 + el;
        Th[fo] = h;
        Tl[fo] = l;
    }
}

// ---------------------------------------------------------------------------
// Split-bf16 MFMA GEMM, B-operand DIRECT from fragment-ordered L2 planes
// (no W LDS staging). A staged in LDS as before. Same fragments, same MFMA
// order -> bit-identical C. LDS padded to ~45KB -> 3 blk/CU VGPR budget.
// ---------------------------------------------------------------------------
__global__ __launch_bounds__(256, 1)
void gemm_mfma_split(const float* __restrict__ A, const unsigned short* __restrict__ Bh,
                     const unsigned short* __restrict__ Bl, const float* __restrict__ bias,
                     float* __restrict__ C, int M, int N, int K)
{
    constexpr int LDT = 56;
    __shared__ unsigned short Ah[128 * LDT];
    __shared__ unsigned short Al[128 * LDT + 8192];   // +16KB pad: pin 3 blk/CU budget

    const int t    = threadIdx.x;
    const int lane = t & 63;
    const int w    = t >> 6;
    const int wr   = w >> 1;
    const int wc   = w & 1;
    const int l15  = lane & 15;
    const int l4   = lane >> 4;
    const int m0   = blockIdx.y * 128;
    const int n0   = blockIdx.x * 128;

    f32x4 acc[4][4];
#pragma unroll
    for (int m = 0; m < 4; ++m)
#pragma unroll
        for (int n = 0; n < 4; ++n) {
            f32x4 z = {0.f, 0.f, 0.f, 0.f};
            acc[m][n] = z;
        }

#pragma unroll 1
    for (int kb = 0; kb < K; kb += 32) {
        __syncthreads();
#pragma unroll
        for (int it = 0; it < 4; ++it) {
            int f   = t + it * 256;
            int row = f >> 3;
            int kg  = (f & 7) * 4;
            float4 av = *(const float4*)&A[(size_t)(m0 + row) * K + kb + kg];
            ushort4 hv, lv;
            hv.x = bf16_rne(av.x); lv.x = bf16_rne(av.x - bf16_up(hv.x));
            hv.y = bf16_rne(av.y); lv.y = bf16_rne(av.y - bf16_up(hv.y));
            hv.z = bf16_rne(av.z); lv.z = bf16_rne(av.z - bf16_up(hv.z));
            hv.w = bf16_rne(av.w); lv.w = bf16_rne(av.w - bf16_up(hv.w));
            *(ushort4*)&Ah[row * LDT + kg] = hv;
            *(ushort4*)&Al[row * LDT + kg] = lv;
        }
        __syncthreads();

        short8 ah[4], al[4], bh[4], bl[4];
#pragma unroll
        for (int m = 0; m < 4; ++m) {
            int row = wr * 64 + m * 16 + l15;
            ah[m] = *(short8*)&Ah[row * LDT + l4 * 8];
            al[m] = *(short8*)&Al[row * LDT + l4 * 8];
        }
        const int kb32 = kb >> 5;
#pragma unroll
        for (int n = 0; n < 4; ++n) {
            const int T = (n0 >> 4) + wc * 4 + n;
            const size_t fo = ((size_t)T * 32 + kb32) * 512 + (size_t)lane * 8;
            bh[n] = *(const short8*)&Bh[fo];
            bl[n] = *(const short8*)&Bl[fo];
        }
#pragma unroll
        for (int m = 0; m < 4; ++m)
#pragma unroll
            for (int n = 0; n < 4; ++n)
                acc[m][n] = __builtin_amdgcn_mfma_f32_16x16x32_bf16(ah[m], bh[n], acc[m][n], 0, 0, 0);
#pragma unroll
        for (int m = 0; m < 4; ++m)
#pragma unroll
            for (int n = 0; n < 4; ++n)
                acc[m][n] = __builtin_amdgcn_mfma_f32_16x16x32_bf16(ah[m], bl[n], acc[m][n], 0, 0, 0);
#pragma unroll
        for (int m = 0; m < 4; ++m)
#pragma unroll
            for (int n = 0; n < 4; ++n)
                acc[m][n] = __builtin_amdgcn_mfma_f32_16x16x32_bf16(al[m], bh[n], acc[m][n], 0, 0, 0);
    }

#pragma unroll
    for (int m = 0; m < 4; ++m) {
        int row = m0 + wr * 64 + m * 16 + l4 * 4;
#pragma unroll
        for (int n = 0; n < 4; ++n) {
            int col = n0 + wc * 64 + n * 16 + l15;
            float bv = bias[col];
#pragma unroll
            for (int r = 0; r < 4; ++r)
                C[(size_t)(row + r) * N + col] = acc[m][n][r] + bv;
        }
    }
}

// ---------------------------------------------------------------------------
// Fused MFMA score + candidate-pruned exact top-k (FLOAT-domain filtering:
// convert only lane-max + <=2 candidates/lane; monotone bijection -> same
// selection set/order -> bit-identical) + softmax + PV gather.
// Score phase identical to R21 (double-buffered, setprio).
// ---------------------------------------------------------------------------
__global__ __launch_bounds__(1024, 1)
void score_select_gather(const float* __restrict__ Qp,
                         const unsigned short* __restrict__ Kf,
                         const float* __restrict__ Vp, float* __restrict__ Oh)
{
    constexpr int LDS_STRIDE = 2049;
    __shared__ float sclds[16][LDS_STRIDE];    // 131136 B
    __shared__ unsigned short Qs[3][16][32];   // 3 KB

    const int t    = threadIdx.x;
    const int lane = t & 63;
    const int wv   = t >> 6;            // 0..15

    const int wgid = blockIdx.x;             // 0..4095
    const int xcd  = wgid & 7;
    const int jj   = wgid >> 3;              // 0..511
    const int bh_  = xcd + 8 * (jj >> 7);    // 0..31
    const int tile = jj & 127;
    const int b    = bh_ >> 4;
    const int h    = bh_ & 15;
    const int lbase = tile * 16;

    // stage + split Q: 16 rows x 32 (all real)
    if (t < 512) {
        int row = t >> 5;       // 0..15
        int col = t & 31;
        float x = Qp[(size_t)(b * L + lbase + row) * (H * R) + h * R + col];
        unsigned short hh = bf16_rne(x);
        float xr = x - bf16_up(hh);
        unsigned short mm = bf16_rne(xr);
        unsigned short ll = bf16_rne(xr - bf16_up(mm));
        Qs[0][row][col] = hh;
        Qs[1][row][col] = mm;
        Qs[2][row][col] = ll;
    }
    __syncthreads();

    const int l15 = lane & 15;
    const int l4  = lane >> 4;

    const short8 ah = *(const short8*)&Qs[0][l15][l4 * 8];
    const short8 am = *(const short8*)&Qs[1][l15][l4 * 8];
    const short8 al = *(const short8*)&Qs[2][l15][l4 * 8];

    const unsigned short* kfb = Kf + (size_t)bh_ * 128 * 1536;

    auto LOADT = [&](int T0, short8& h0, short8& m0v, short8& l0v,
                     short8& h1, short8& m1v, short8& l1v) {
        const unsigned short* t0 = kfb + (size_t)T0 * 1536 + lane * 8;
        h0  = *(const short8*)(t0);
        m0v = *(const short8*)(t0 + 512);
        l0v = *(const short8*)(t0 + 1024);
        h1  = *(const short8*)(t0 + 1536);
        m1v = *(const short8*)(t0 + 2048);
        l1v = *(const short8*)(t0 + 2560);
    };
    auto COMPUTE = [&](const short8& bh0, const short8& bm0, const short8& bl0,
                       const short8& bh1, const short8& bm1, const short8& bl1, int p) {
        f32x4 acc0 = {0.f, 0.f, 0.f, 0.f};
        f32x4 acc1 = {0.f, 0.f, 0.f, 0.f};
        __builtin_amdgcn_s_setprio(1);
        acc0 = __builtin_amdgcn_mfma_f32_16x16x32_bf16(ah, bh0, acc0, 0, 0, 0);
        acc1 = __builtin_amdgcn_mfma_f32_16x16x32_bf16(ah, bh1, acc1, 0, 0, 0);
        acc0 = __builtin_amdgcn_mfma_f32_16x16x32_bf16(ah, bm0, acc0, 0, 0, 0);
        acc1 = __builtin_amdgcn_mfma_f32_16x16x32_bf16(ah, bm1, acc1, 0, 0, 0);
        acc0 = __builtin_amdgcn_mfma_f32_16x16x32_bf16(am, bh0, acc0, 0, 0, 0);
        acc1 = __builtin_amdgcn_mfma_f32_16x16x32_bf16(am, bh1, acc1, 0, 0, 0);
        acc0 = __builtin_amdgcn_mfma_f32_16x16x32_bf16(am, bm0, acc0, 0, 0, 0);
        acc1 = __builtin_amdgcn_mfma_f32_16x16x32_bf16(am, bm1, acc1, 0, 0, 0);
        acc0 = __builtin_amdgcn_mfma_f32_16x16x32_bf16(ah, bl0, acc0, 0, 0, 0);
        acc1 = __builtin_amdgcn_mfma_f32_16x16x32_bf16(ah, bl1, acc1, 0, 0, 0);
        acc0 = __builtin_amdgcn_mfma_f32_16x16x32_bf16(al, bh0, acc0, 0, 0, 0);
        acc1 = __builtin_amdgcn_mfma_f32_16x16x32_bf16(al, bh1, acc1, 0, 0, 0);
        __builtin_amdgcn_s_setprio(0);
        const int kc0 = wv * 128 + p * 32 + l15;
#pragma unroll
        for (int r = 0; r < 4; ++r) {
            sclds[l4 * 4 + r][kc0]      = acc0[r];
            sclds[l4 * 4 + r][kc0 + 16] = acc1[r];
        }
    };

    {
        short8 xh0, xm0, xl0, xh1, xm1, xl1;
        short8 yh0, ym0, yl0, yh1, ym1, yl1;
        LOADT(wv * 8 + 0, xh0, xm0, xl0, xh1, xm1, xl1);
        LOADT(wv * 8 + 2, yh0, ym0, yl0, yh1, ym1, yl1);
        COMPUTE(xh0, xm0, xl0, xh1, xm1, xl1, 0);
        LOADT(wv * 8 + 4, xh0, xm0, xl0, xh1, xm1, xl1);
        COMPUTE(yh0, ym0, yl0, yh1, ym1, yl1, 1);
        LOADT(wv * 8 + 6, yh0, ym0, yl0, yh1, ym1, yl1);
        COMPUTE(xh0, xm0, xl0, xh1, xm1, xl1, 2);
        COMPUTE(yh0, ym0, yl0, yh1, ym1, yl1, 3);
    }

    __syncthreads();

    const unsigned long long lanelt = (1ull << lane) - 1ull;
    {
        const int r = wv;   // one row per wave

        float sreg[32];
#pragma unroll
        for (int j = 0; j < 32; ++j) sreg[j] = sclds[r][j * 64 + lane];

        // lane max + wave max, float domain
        float lmaxf = sreg[0];
#pragma unroll
        for (int j = 1; j < 32; ++j) lmaxf = fmaxf(lmaxf, sreg[j]);
        float mx = lmaxf;
#pragma unroll
        for (int off = 32; off >= 1; off >>= 1)
            mx = fmaxf(mx, __shfl_xor(mx, off, 64));

        // M32 = exact 32nd-largest lane-max (radix on the single converted value)
        const unsigned int lmax = to_sortable(lmaxf);
        unsigned int PM = 0;
        for (int bit = 31; bit >= 0; --bit) {
            unsigned int test = PM | (1u << bit);
            int c2 = (int)__popcll(__ballot(lmax >= test));
            if (c2 >= TOPK) {
                PM = test;
                if (c2 == TOPK) break;
            }
        }
        const float TM = inv_sortable(PM);   // float threshold; {s>=TM} == {u>=PM}

        // compact candidates (float compares, store float + idx)
        int cbase = 0;
#pragma unroll
        for (int j = 0; j < 32; ++j) {
            bool alive = (sreg[j] >= TM);
            unsigned long long m = __ballot(alive);
            if (alive) {
                int pos = cbase + (int)__popcll(m & lanelt);
                if (pos < 128) {
                    sclds[r][1024 + pos] = sreg[j];
                    sclds[r][1280 + pos] = __uint_as_float((unsigned int)(j * 64 + lane));
                }
            }
            cbase += (int)__popcll(m);
        }
        const int Ncand = cbase;

        float dsum = 0.f;
        int   base = 0;

        if (Ncand <= 128) {
            const bool v0 = lane < Ncand;
            const bool v1 = 64 + lane < Ncand;
            const float c0f = v0 ? sclds[r][1024 + lane]      : 0.f;
            const float c1f = v1 ? sclds[r][1024 + 64 + lane] : 0.f;
            const unsigned int i0 = v0 ? __float_as_uint(sclds[r][1280 + lane])      : 0u;
            const unsigned int i1 = v1 ? __float_as_uint(sclds[r][1280 + 64 + lane]) : 0u;
            const unsigned int cu0 = v0 ? to_sortable(c0f) : 0u;
            const unsigned int cu1 = v1 ? to_sortable(c1f) : 0u;

            unsigned int P = 0;
            for (int bit = 31; bit >= 0; --bit) {
                unsigned int test = P | (1u << bit);
                int c2 = (int)__popcll(__ballot(v0 && cu0 >= test))
                       + (int)__popcll(__ballot(v1 && cu1 >= test));
                if (c2 >= TOPK) {
                    P = test;
                    if (c2 == TOPK) break;
                }
            }

            {
                bool sel = v0 && (cu0 >= P);
                unsigned long long m = __ballot(sel);
                if (sel) {
                    float e = __expf(c0f - mx);
                    int pos = (int)__popcll(m & lanelt);
                    if (pos < SELCAP) {
                        sclds[r][pos]       = e;
                        sclds[r][512 + pos] = __uint_as_float(i0);
                    }
                    dsum += e;
                }
                base = (int)__popcll(m);
            }
            {
                bool sel = v1 && (cu1 >= P);
                unsigned long long m = __ballot(sel);
                if (sel) {
                    float e = __expf(c1f - mx);
                    int pos = base + (int)__popcll(m & lanelt);
                    if (pos < SELCAP) {
                        sclds[r][pos]       = e;
                        sclds[r][512 + pos] = __uint_as_float(i1);
                    }
                    dsum += e;
                }
                base += (int)__popcll(m);
            }
        } else {
            // fallback (adversarial ties): full radix in sortable domain
            unsigned int u[32];
#pragma unroll
            for (int j = 0; j < 32; ++j) u[j] = to_sortable(sreg[j]);
            unsigned int P = 0;
            for (int bit = 31; bit >= 0; --bit) {
                unsigned int test = P | (1u << bit);
                int c2 = 0;
#pragma unroll
                for (int j = 0; j < 32; ++j)
                    c2 += (int)__popcll(__ballot(u[j] >= test));
                if (c2 >= TOPK) {
                    P = test;
                    if (c2 == TOPK) break;
                }
            }
#pragma unroll
            for (int j = 0; j < 32; ++j) {
                bool sel = (u[j] >= P);
                unsigned long long m = __ballot(sel);
                if (sel) {
                    float e = __expf(sreg[j] - mx);
                    int pos = base + (int)__popcll(m & lanelt);
                    if (pos < SELCAP) {
                        sclds[r][pos]       = e;
                        sclds[r][512 + pos] = __uint_as_float((unsigned int)(j * 64 + lane));
                    }
                    dsum += e;
                }
                base += (int)__popcll(m);
            }
        }
#pragma unroll
        for (int off = 32; off >= 1; off >>= 1)
            dsum += __shfl_xor(dsum, off, 64);

        // ---- PV gather, 8-deep ILP ----
        const int cn = base < SELCAP ? base : SELCAP;
        const float inv = 1.0f / dsum;
        const float* vb = Vp + (size_t)b * S * DM + h * DH + lane;

        float a0 = 0.f, a1 = 0.f, a2 = 0.f, a3 = 0.f;
        float a4 = 0.f, a5 = 0.f, a6 = 0.f, a7 = 0.f;
        int tt = 0;
        for (; tt + 8 <= cn; tt += 8) {
            int   s0 = (int)__float_as_uint(sclds[r][512 + tt + 0]);
            int   s1 = (int)__float_as_uint(sclds[r][512 + tt + 1]);
            int   s2 = (int)__float_as_uint(sclds[r][512 + tt + 2]);
            int   s3 = (int)__float_as_uint(sclds[r][512 + tt + 3]);
            int   s4 = (int)__float_as_uint(sclds[r][512 + tt + 4]);
            int   s5 = (int)__float_as_uint(sclds[r][512 + tt + 5]);
            int   s6 = (int)__float_as_uint(sclds[r][512 + tt + 6]);
            int   s7 = (int)__float_as_uint(sclds[r][512 + tt + 7]);
            float w0 = sclds[r][tt + 0], w1 = sclds[r][tt + 1];
            float w2 = sclds[r][tt + 2], w3 = sclds[r][tt + 3];
            float w4 = sclds[r][tt + 4], w5 = sclds[r][tt + 5];
            float w6 = sclds[r][tt + 6], w7 = sclds[r][tt + 7];
            a0 = fmaf(w0, vb[(size_t)s0 * DM], a0);
            a1 = fmaf(w1, vb[(size_t)s1 * DM], a1);
            a2 = fmaf(w2, vb[(size_t)s2 * DM], a2);
            a3 = fmaf(w3, vb[(size_t)s3 * DM], a3);
            a4 = fmaf(w4, vb[(size_t)s4 * DM], a4);
            a5 = fmaf(w5, vb[(size_t)s5 * DM], a5);
            a6 = fmaf(w6, vb[(size_t)s6 * DM], a6);
            a7 = fmaf(w7, vb[(size_t)s7 * DM], a7);
        }
        for (; tt < cn; ++tt) {
            int s0 = (int)__float_as_uint(sclds[r][512 + tt]);
            a0 = fmaf(sclds[r][tt], vb[(size_t)s0 * DM], a0);
        }
        Oh[(size_t)(b * L + lbase + r) * DM + h * DH + lane] =
            (((a0 + a1) + (a2 + a3)) + ((a4 + a5) + (a6 + a7))) * inv;
    }
}

// ---------------------------------------------------------------------------
extern "C" void kernel_launch(void* const* d_in, const int* in_sizes, int n_in,
                              void* d_out, int out_size, void* d_ws, size_t ws_size,
                              hipStream_t stream)
{
    const float* q  = (const float*)d_in[0];
    const float* k  = (const float*)d_in[1];
    const float* v  = (const float*)d_in[2];
    const float* Wq = (const float*)d_in[3];
    const float* bq = (const float*)d_in[4];
    const float* Wk = (const float*)d_in[5];
    const float* bk = (const float*)d_in[6];
    const float* Wv = (const float*)d_in[7];
    const float* bv = (const float*)d_in[8];
    const float* Wo = (const float*)d_in[9];
    const float* bo = (const float*)d_in[10];
    // d_in[11] = pos_bias: per-head additive constant -> top-k/softmax invariant -> no-op.

    float* out = (float*)d_out;
    char*  ws  = (char*)d_ws;

    const size_t MB = 1024 * 1024;
    float*          Qp = (float*)(ws);                       //  0-8 MiB
    unsigned short* Kf = (unsigned short*)(ws + 8 * MB);     //  8-20 MiB (fragment-ordered)
    float*          Vp = (float*)(ws + 20 * MB);             // 20-36
    float*          Oh = (float*)(ws + 36 * MB);             // 36-52
    unsigned short* WvH = (unsigned short*)(ws + 36 * MB);   // overlaps Oh head (dead until attn)
    unsigned short* WvL = (unsigned short*)(ws + 38 * MB);
    unsigned short* WoH = (unsigned short*)(ws + 52 * MB);   // 52-54
    unsigned short* WoL = (unsigned short*)(ws + 54 * MB);   // 54-56

    const int M = B * L;  // 4096
    dim3 blk(256);

    transpose_split_dual<<<dim3(DM / 32, DM / 32, 2), blk, 0, stream>>>(
        Wv, WvH, WvL, Wo, WoH, WoL, DM, DM);

    gemm_mfma_split<<<dim3(DM / 128, M / 128), blk, 0, stream>>>(v, WvH, WvL, bv, Vp, M, DM, DM);

    qk_proj<<<dim3((H * R) / 128, M / 128, 2), blk, 0, stream>>>(
        q, Wq, bq, Qp, k, Wk, bk, Kf, M, H * R, DM);

    score_select_gather<<<dim3(4096), dim3(1024), 0, stream>>>(Qp, Kf, Vp, Oh);

    gemm_mfma_split<<<dim3(DM / 128, M / 128), blk, 0, stream>>>(Oh, WoH, WoL, bo, out, M, DM, DM);
}

// Round 24
// 466.454 us; speedup vs baseline: 1.0256x; 1.0256x over previous
//
#include <hip/hip_runtime.h>
#include <hip/hip_bf16.h>
#include <cstdint>

// Problem constants (match setup_inputs)
constexpr int B  = 2;
constexpr int L  = 2048;
constexpr int S  = 2048;
constexpr int DM = 1024;
constexpr int H  = 16;
constexpr int R  = 32;     // rank
constexpr int DH = 64;     // head dim
constexpr int TOPK = 32;
constexpr int SELCAP = 36;
constexpr float SCALE = 0.17677669529663687f; // 1/sqrt(32)

// MEASURED (R4-R23): VGPR cap = LDS-implied occupancy; LICM -> opaque-zero
// asm. R23 FAILED: MFMA'ing the Q/K PROJECTIONS perturbs projection values
// (~1e-5) -> top-k tie flips -> absmax 1.4e-2. Q/K projections MUST stay
// fp32-vector (correctness constraint). Score-phase MFMA (R16) is safe
// because projections feeding selection stay bit-identical.
// This round: best-of assembly of all PASSING configs (R22 attn + R12 fp32
// qk_proj + R21 GEMMs) ~= 466us.

using short8 = __attribute__((ext_vector_type(8))) short;
using f32x4  = __attribute__((ext_vector_type(4))) float;

__device__ __forceinline__ unsigned short bf16_rne(float x) {
    unsigned int u = __float_as_uint(x);
    unsigned int r = u + 0x7FFFu + ((u >> 16) & 1u);
    return (unsigned short)(r >> 16);
}
__device__ __forceinline__ float bf16_up(unsigned short h) {
    return __uint_as_float((unsigned int)h << 16);
}
__device__ __forceinline__ unsigned int to_sortable(float f) {
    unsigned int bb  = __float_as_uint(f);
    unsigned int sgn = (unsigned int)(((int)bb) >> 31);
    return bb ^ (sgn | 0x80000000u);
}
__device__ __forceinline__ float inv_sortable(unsigned int uu) {
    unsigned int sg2 = (unsigned int)(((int)uu) >> 31);
    return __uint_as_float(uu ^ (0x80000000u | ~sg2));
}

// ---------------------------------------------------------------------------
// Merged Q/K projection, fp32 vector (R12-proven bit-exact path that feeds
// top-k). z=0: Q -> fp32 Qp (pre-scaled). z=1: K -> 3-term bf16 splits in
// MFMA-fragment order (R17 layout).
// ---------------------------------------------------------------------------
__global__ __launch_bounds__(256, 2)
void qk_proj(const float* __restrict__ Aq, const float* __restrict__ Wq_,
             const float* __restrict__ bq_, float* __restrict__ Qp,
             const float* __restrict__ Ak, const float* __restrict__ Wk_,
             const float* __restrict__ bk_, unsigned short* __restrict__ Kf,
             int M, int N, int K)
{
    const int z = blockIdx.z;
    const float* A    = z ? Ak  : Aq;
    const float* W    = z ? Wk_ : Wq_;
    const float* bias = z ? bk_ : bq_;

    __shared__ float As[16][136];
    __shared__ float Ws[16][132];

    const int t  = threadIdx.x;
    const int tx = t & 15;
    const int ty = t >> 4;
    const int m0 = blockIdx.y * 128;
    const int n0 = blockIdx.x * 128;

    float acc[8][8];
#pragma unroll
    for (int i = 0; i < 8; ++i)
#pragma unroll
        for (int j = 0; j < 8; ++j) acc[i][j] = 0.f;

    for (int kb = 0; kb < K; kb += 16) {
        __syncthreads();
#pragma unroll
        for (int it = 0; it < 2; ++it) {
            int f4  = t + it * 256;
            int row = f4 >> 2;
            int cg  = (f4 & 3) * 4;
            float4 av = *(const float4*)&A[(size_t)(m0 + row) * K + kb + cg];
            As[cg + 0][row] = av.x;
            As[cg + 1][row] = av.y;
            As[cg + 2][row] = av.z;
            As[cg + 3][row] = av.w;
        }
#pragma unroll
        for (int it = 0; it < 2; ++it) {
            int f4 = t + it * 256;
            int kk = f4 >> 5;
            int cb = (f4 & 31) * 4;
            *(float4*)&Ws[kk][cb] = *(const float4*)&W[(size_t)(kb + kk) * N + n0 + cb];
        }
        __syncthreads();
#pragma unroll
        for (int kk = 0; kk < 16; ++kk) {
            float4 a0 = *(const float4*)&As[kk][ty * 8];
            float4 a1 = *(const float4*)&As[kk][ty * 8 + 4];
            float4 w0 = *(const float4*)&Ws[kk][tx * 8];
            float4 w1 = *(const float4*)&Ws[kk][tx * 8 + 4];
            float a[8] = {a0.x, a0.y, a0.z, a0.w, a1.x, a1.y, a1.z, a1.w};
            float w[8] = {w0.x, w0.y, w0.z, w0.w, w1.x, w1.y, w1.z, w1.w};
#pragma unroll
            for (int i = 0; i < 8; ++i)
#pragma unroll
                for (int j = 0; j < 8; ++j)
                    acc[i][j] = fmaf(a[i], w[j], acc[i][j]);
        }
    }

    float4 b0 = *(const float4*)&bias[n0 + tx * 8];
    float4 b1 = *(const float4*)&bias[n0 + tx * 8 + 4];

    if (z == 0) {
#pragma unroll
        for (int i = 0; i < 8; ++i) {
            float4 o0 = make_float4((acc[i][0] + b0.x) * SCALE, (acc[i][1] + b0.y) * SCALE,
                                    (acc[i][2] + b0.z) * SCALE, (acc[i][3] + b0.w) * SCALE);
            float4 o1 = make_float4((acc[i][4] + b1.x) * SCALE, (acc[i][5] + b1.y) * SCALE,
                                    (acc[i][6] + b1.z) * SCALE, (acc[i][7] + b1.w) * SCALE);
            size_t off = (size_t)(m0 + ty * 8 + i) * N + n0 + tx * 8;
            *(float4*)&Qp[off]     = o0;
            *(float4*)&Qp[off + 4] = o1;
        }
    } else {
        float bb[8] = {b0.x, b0.y, b0.z, b0.w, b1.x, b1.y, b1.z, b1.w};
        const int h2 = (n0 + tx * 8) >> 5;
        const int l4 = ((n0 + tx * 8) & 31) >> 3;
#pragma unroll
        for (int i = 0; i < 8; ++i) {
            unsigned short hh[8], mm[8], ll[8];
#pragma unroll
            for (int j = 0; j < 8; ++j) {
                float x = acc[i][j] + bb[j];
                hh[j] = bf16_rne(x);
                float xr = x - bf16_up(hh[j]);
                mm[j] = bf16_rne(xr);
                ll[j] = bf16_rne(xr - bf16_up(mm[j]));
            }
            const int grow = m0 + ty * 8 + i;
            const int bat  = grow >> 11;
            const int key  = grow & 2047;
            const int T    = key >> 4;
            const int l15  = key & 15;
            const size_t base = (((size_t)(bat * H + h2) * 128 + T) * 1536)
                              + (size_t)(l4 * 16 + l15) * 8;
            ushort4 h0v = {hh[0], hh[1], hh[2], hh[3]}, h1v = {hh[4], hh[5], hh[6], hh[7]};
            ushort4 m0v = {mm[0], mm[1], mm[2], mm[3]}, m1v = {mm[4], mm[5], mm[6], mm[7]};
            ushort4 l0v = {ll[0], ll[1], ll[2], ll[3]}, l1v = {ll[4], ll[5], ll[6], ll[7]};
            *(ushort4*)&Kf[base]            = h0v;
            *(ushort4*)&Kf[base + 4]        = h1v;
            *(ushort4*)&Kf[base + 512]      = m0v;
            *(ushort4*)&Kf[base + 512 + 4]  = m1v;
            *(ushort4*)&Kf[base + 1024]     = l0v;
            *(ushort4*)&Kf[base + 1024 + 4] = l1v;
        }
    }
}

// ---------------------------------------------------------------------------
// Dual transpose + split (R12-proven, row-major [N][K], 2-term).
// ---------------------------------------------------------------------------
__global__ __launch_bounds__(256)
void transpose_split_dual(const float* __restrict__ Wv_, unsigned short* __restrict__ VhT,
                          unsigned short* __restrict__ VlT,
                          const float* __restrict__ Wo_, unsigned short* __restrict__ OhT,
                          unsigned short* __restrict__ OlT, int N, int K)
{
    const int z = blockIdx.z;
    const float* W = z ? Wo_ : Wv_;
    unsigned short* Th = z ? OhT : VhT;
    unsigned short* Tl = z ? OlT : VlT;

    __shared__ float tile[32][33];
    const int n0 = blockIdx.x * 32;
    const int k0 = blockIdx.y * 32;
    const int tx = threadIdx.x & 31;
    const int ty = threadIdx.x >> 5;

#pragma unroll
    for (int i = ty; i < 32; i += 8)
        tile[i][tx] = W[(size_t)(k0 + i) * N + n0 + tx];
    __syncthreads();
#pragma unroll
    for (int i = ty; i < 32; i += 8) {
        float x = tile[tx][i];
        unsigned short h = bf16_rne(x);
        float hf = bf16_up(h);
        unsigned short l = bf16_rne(x - hf);
        Th[(size_t)(n0 + i) * K + k0 + tx] = h;
        Tl[(size_t)(n0 + i) * K + k0 + tx] = l;
    }
}

// ---------------------------------------------------------------------------
// Split-bf16 MFMA GEMM (R21-proven, LDS-staged A and B).
// ---------------------------------------------------------------------------
__global__ __launch_bounds__(256, 1)
void gemm_mfma_split(const float* __restrict__ A, const unsigned short* __restrict__ Bh,
                     const unsigned short* __restrict__ Bl, const float* __restrict__ bias,
                     float* __restrict__ C, int M, int N, int K)
{
    constexpr int LDT = 56;
    __shared__ unsigned short Ah[128 * LDT];
    __shared__ unsigned short Al[128 * LDT];
    __shared__ unsigned short Wh[128 * LDT];
    __shared__ unsigned short Wl[128 * LDT];

    const int t    = threadIdx.x;
    const int lane = t & 63;
    const int w    = t >> 6;
    const int wr   = w >> 1;
    const int wc   = w & 1;
    const int l15  = lane & 15;
    const int l4   = lane >> 4;
    const int m0   = blockIdx.y * 128;
    const int n0   = blockIdx.x * 128;

    f32x4 acc[4][4];
#pragma unroll
    for (int m = 0; m < 4; ++m)
#pragma unroll
        for (int n = 0; n < 4; ++n) {
            f32x4 z = {0.f, 0.f, 0.f, 0.f};
            acc[m][n] = z;
        }

#pragma unroll 1
    for (int kb = 0; kb < K; kb += 32) {
        __syncthreads();
#pragma unroll
        for (int it = 0; it < 4; ++it) {
            int f   = t + it * 256;
            int row = f >> 3;
            int kg  = (f & 7) * 4;
            float4 av = *(const float4*)&A[(size_t)(m0 + row) * K + kb + kg];
            ushort4 hv, lv;
            hv.x = bf16_rne(av.x); lv.x = bf16_rne(av.x - bf16_up(hv.x));
            hv.y = bf16_rne(av.y); lv.y = bf16_rne(av.y - bf16_up(hv.y));
            hv.z = bf16_rne(av.z); lv.z = bf16_rne(av.z - bf16_up(hv.z));
            hv.w = bf16_rne(av.w); lv.w = bf16_rne(av.w - bf16_up(hv.w));
            *(ushort4*)&Ah[row * LDT + kg] = hv;
            *(ushort4*)&Al[row * LDT + kg] = lv;
            ushort4 bh4 = *(const ushort4*)&Bh[(size_t)(n0 + row) * K + kb + kg];
            ushort4 bl4 = *(const ushort4*)&Bl[(size_t)(n0 + row) * K + kb + kg];
            *(ushort4*)&Wh[row * LDT + kg] = bh4;
            *(ushort4*)&Wl[row * LDT + kg] = bl4;
        }
        __syncthreads();

        short8 ah[4], al[4], bh[4], bl[4];
#pragma unroll
        for (int m = 0; m < 4; ++m) {
            int row = wr * 64 + m * 16 + l15;
            ah[m] = *(short8*)&Ah[row * LDT + l4 * 8];
            al[m] = *(short8*)&Al[row * LDT + l4 * 8];
        }
#pragma unroll
        for (int n = 0; n < 4; ++n) {
            int col = wc * 64 + n * 16 + l15;
            bh[n] = *(short8*)&Wh[col * LDT + l4 * 8];
            bl[n] = *(short8*)&Wl[col * LDT + l4 * 8];
        }
#pragma unroll
        for (int m = 0; m < 4; ++m)
#pragma unroll
            for (int n = 0; n < 4; ++n)
                acc[m][n] = __builtin_amdgcn_mfma_f32_16x16x32_bf16(ah[m], bh[n], acc[m][n], 0, 0, 0);
#pragma unroll
        for (int m = 0; m < 4; ++m)
#pragma unroll
            for (int n = 0; n < 4; ++n)
                acc[m][n] = __builtin_amdgcn_mfma_f32_16x16x32_bf16(ah[m], bl[n], acc[m][n], 0, 0, 0);
#pragma unroll
        for (int m = 0; m < 4; ++m)
#pragma unroll
            for (int n = 0; n < 4; ++n)
                acc[m][n] = __builtin_amdgcn_mfma_f32_16x16x32_bf16(al[m], bh[n], acc[m][n], 0, 0, 0);
    }

#pragma unroll
    for (int m = 0; m < 4; ++m) {
        int row = m0 + wr * 64 + m * 16 + l4 * 4;
#pragma unroll
        for (int n = 0; n < 4; ++n) {
            int col = n0 + wc * 64 + n * 16 + l15;
            float bv = bias[col];
#pragma unroll
            for (int r = 0; r < 4; ++r)
                C[(size_t)(row + r) * N + col] = acc[m][n][r] + bv;
        }
    }
}

// ---------------------------------------------------------------------------
// Fused MFMA score + candidate-pruned exact top-k (float-domain) + softmax +
// PV gather (R22-proven, 207us).
// ---------------------------------------------------------------------------
__global__ __launch_bounds__(1024, 1)
void score_select_gather(const float* __restrict__ Qp,
                         const unsigned short* __restrict__ Kf,
                         const float* __restrict__ Vp, float* __restrict__ Oh)
{
    constexpr int LDS_STRIDE = 2049;
    __shared__ float sclds[16][LDS_STRIDE];    // 131136 B
    __shared__ unsigned short Qs[3][16][32];   // 3 KB

    const int t    = threadIdx.x;
    const int lane = t & 63;
    const int wv   = t >> 6;            // 0..15

    const int wgid = blockIdx.x;             // 0..4095
    const int xcd  = wgid & 7;
    const int jj   = wgid >> 3;              // 0..511
    const int bh_  = xcd + 8 * (jj >> 7);    // 0..31
    const int tile = jj & 127;
    const int b    = bh_ >> 4;
    const int h    = bh_ & 15;
    const int lbase = tile * 16;

    if (t < 512) {
        int row = t >> 5;
        int col = t & 31;
        float x = Qp[(size_t)(b * L + lbase + row) * (H * R) + h * R + col];
        unsigned short hh = bf16_rne(x);
        float xr = x - bf16_up(hh);
        unsigned short mm = bf16_rne(xr);
        unsigned short ll = bf16_rne(xr - bf16_up(mm));
        Qs[0][row][col] = hh;
        Qs[1][row][col] = mm;
        Qs[2][row][col] = ll;
    }
    __syncthreads();

    const int l15 = lane & 15;
    const int l4  = lane >> 4;

    const short8 ah = *(const short8*)&Qs[0][l15][l4 * 8];
    const short8 am = *(const short8*)&Qs[1][l15][l4 * 8];
    const short8 al = *(const short8*)&Qs[2][l15][l4 * 8];

    const unsigned short* kfb = Kf + (size_t)bh_ * 128 * 1536;

    auto LOADT = [&](int T0, short8& h0, short8& m0v, short8& l0v,
                     short8& h1, short8& m1v, short8& l1v) {
        const unsigned short* t0 = kfb + (size_t)T0 * 1536 + lane * 8;
        h0  = *(const short8*)(t0);
        m0v = *(const short8*)(t0 + 512);
        l0v = *(const short8*)(t0 + 1024);
        h1  = *(const short8*)(t0 + 1536);
        m1v = *(const short8*)(t0 + 2048);
        l1v = *(const short8*)(t0 + 2560);
    };
    auto COMPUTE = [&](const short8& bh0, const short8& bm0, const short8& bl0,
                       const short8& bh1, const short8& bm1, const short8& bl1, int p) {
        f32x4 acc0 = {0.f, 0.f, 0.f, 0.f};
        f32x4 acc1 = {0.f, 0.f, 0.f, 0.f};
        __builtin_amdgcn_s_setprio(1);
        acc0 = __builtin_amdgcn_mfma_f32_16x16x32_bf16(ah, bh0, acc0, 0, 0, 0);
        acc1 = __builtin_amdgcn_mfma_f32_16x16x32_bf16(ah, bh1, acc1, 0, 0, 0);
        acc0 = __builtin_amdgcn_mfma_f32_16x16x32_bf16(ah, bm0, acc0, 0, 0, 0);
        acc1 = __builtin_amdgcn_mfma_f32_16x16x32_bf16(ah, bm1, acc1, 0, 0, 0);
        acc0 = __builtin_amdgcn_mfma_f32_16x16x32_bf16(am, bh0, acc0, 0, 0, 0);
        acc1 = __builtin_amdgcn_mfma_f32_16x16x32_bf16(am, bh1, acc1, 0, 0, 0);
        acc0 = __builtin_amdgcn_mfma_f32_16x16x32_bf16(am, bm0, acc0, 0, 0, 0);
        acc1 = __builtin_amdgcn_mfma_f32_16x16x32_bf16(am, bm1, acc1, 0, 0, 0);
        acc0 = __builtin_amdgcn_mfma_f32_16x16x32_bf16(ah, bl0, acc0, 0, 0, 0);
        acc1 = __builtin_amdgcn_mfma_f32_16x16x32_bf16(ah, bl1, acc1, 0, 0, 0);
        acc0 = __builtin_amdgcn_mfma_f32_16x16x32_bf16(al, bh0, acc0, 0, 0, 0);
        acc1 = __builtin_amdgcn_mfma_f32_16x16x32_bf16(al, bh1, acc1, 0, 0, 0);
        __builtin_amdgcn_s_setprio(0);
        const int kc0 = wv * 128 + p * 32 + l15;
#pragma unroll
        for (int r = 0; r < 4; ++r) {
            sclds[l4 * 4 + r][kc0]      = acc0[r];
            sclds[l4 * 4 + r][kc0 + 16] = acc1[r];
        }
    };

    {
        short8 xh0, xm0, xl0, xh1, xm1, xl1;
        short8 yh0, ym0, yl0, yh1, ym1, yl1;
        LOADT(wv * 8 + 0, xh0, xm0, xl0, xh1, xm1, xl1);
        LOADT(wv * 8 + 2, yh0, ym0, yl0, yh1, ym1, yl1);
        COMPUTE(xh0, xm0, xl0, xh1, xm1, xl1, 0);
        LOADT(wv * 8 + 4, xh0, xm0, xl0, xh1, xm1, xl1);
        COMPUTE(yh0, ym0, yl0, yh1, ym1, yl1, 1);
        LOADT(wv * 8 + 6, yh0, ym0, yl0, yh1, ym1, yl1);
        COMPUTE(xh0, xm0, xl0, xh1, xm1, xl1, 2);
        COMPUTE(yh0, ym0, yl0, yh1, ym1, yl1, 3);
    }

    __syncthreads();

    const unsigned long long lanelt = (1ull << lane) - 1ull;
    {
        const int r = wv;

        float sreg[32];
#pragma unroll
        for (int j = 0; j < 32; ++j) sreg[j] = sclds[r][j * 64 + lane];

        float lmaxf = sreg[0];
#pragma unroll
        for (int j = 1; j < 32; ++j) lmaxf = fmaxf(lmaxf, sreg[j]);
        float mx = lmaxf;
#pragma unroll
        for (int off = 32; off >= 1; off >>= 1)
            mx = fmaxf(mx, __shfl_xor(mx, off, 64));

        const unsigned int lmax = to_sortable(lmaxf);
        unsigned int PM = 0;
        for (int bit = 31; bit >= 0; --bit) {
            unsigned int test = PM | (1u << bit);
            int c2 = (int)__popcll(__ballot(lmax >= test));
            if (c2 >= TOPK) {
                PM = test;
                if (c2 == TOPK) break;
            }
        }
        const float TM = inv_sortable(PM);

        int cbase = 0;
#pragma unroll
        for (int j = 0; j < 32; ++j) {
            bool alive = (sreg[j] >= TM);
            unsigned long long m = __ballot(alive);
            if (alive) {
                int pos = cbase + (int)__popcll(m & lanelt);
                if (pos < 128) {
                    sclds[r][1024 + pos] = sreg[j];
                    sclds[r][1280 + pos] = __uint_as_float((unsigned int)(j * 64 + lane));
                }
            }
            cbase += (int)__popcll(m);
        }
        const int Ncand = cbase;

        float dsum = 0.f;
        int   base = 0;

        if (Ncand <= 128) {
            const bool v0 = lane < Ncand;
            const bool v1 = 64 + lane < Ncand;
            const float c0f = v0 ? sclds[r][1024 + lane]      : 0.f;
            const float c1f = v1 ? sclds[r][1024 + 64 + lane] : 0.f;
            const unsigned int i0 = v0 ? __float_as_uint(sclds[r][1280 + lane])      : 0u;
            const unsigned int i1 = v1 ? __float_as_uint(sclds[r][1280 + 64 + lane]) : 0u;
            const unsigned int cu0 = v0 ? to_sortable(c0f) : 0u;
            const unsigned int cu1 = v1 ? to_sortable(c1f) : 0u;

            unsigned int P = 0;
            for (int bit = 31; bit >= 0; --bit) {
                unsigned int test = P | (1u << bit);
                int c2 = (int)__popcll(__ballot(v0 && cu0 >= test))
                       + (int)__popcll(__ballot(v1 && cu1 >= test));
                if (c2 >= TOPK) {
                    P = test;
                    if (c2 == TOPK) break;
                }
            }

            {
                bool sel = v0 && (cu0 >= P);
                unsigned long long m = __ballot(sel);
                if (sel) {
                    float e = __expf(c0f - mx);
                    int pos = (int)__popcll(m & lanelt);
                    if (pos < SELCAP) {
                        sclds[r][pos]       = e;
                        sclds[r][512 + pos] = __uint_as_float(i0);
                    }
                    dsum += e;
                }
                base = (int)__popcll(m);
            }
            {
                bool sel = v1 && (cu1 >= P);
                unsigned long long m = __ballot(sel);
                if (sel) {
                    float e = __expf(c1f - mx);
                    int pos = base + (int)__popcll(m & lanelt);
                    if (pos < SELCAP) {
                        sclds[r][pos]       = e;
                        sclds[r][512 + pos] = __uint_as_float(i1);
                    }
                    dsum += e;
                }
                base += (int)__popcll(m);
            }
        } else {
            unsigned int u[32];
#pragma unroll
            for (int j = 0; j < 32; ++j) u[j] = to_sortable(sreg[j]);
            unsigned int P = 0;
            for (int bit = 31; bit >= 0; --bit) {
                unsigned int test = P | (1u << bit);
                int c2 = 0;
#pragma unroll
                for (int j = 0; j < 32; ++j)
                    c2 += (int)__popcll(__ballot(u[j] >= test));
                if (c2 >= TOPK) {
                    P = test;
                    if (c2 == TOPK) break;
                }
            }
#pragma unroll
            for (int j = 0; j < 32; ++j) {
                bool sel = (u[j] >= P);
                unsigned long long m = __ballot(sel);
                if (sel) {
                    float e = __expf(sreg[j] - mx);
                    int pos = base + (int)__popcll(m & lanelt);
                    if (pos < SELCAP) {
                        sclds[r][pos]       = e;
                        sclds[r][512 + pos] = __uint_as_float((unsigned int)(j * 64 + lane));
                    }
                    dsum += e;
                }
                base += (int)__popcll(m);
            }
        }
#pragma unroll
        for (int off = 32; off >= 1; off >>= 1)
            dsum += __shfl_xor(dsum, off, 64);

        const int cn = base < SELCAP ? base : SELCAP;
        const float inv = 1.0f / dsum;
        const float* vb = Vp + (size_t)b * S * DM + h * DH + lane;

        float a0 = 0.f, a1 = 0.f, a2 = 0.f, a3 = 0.f;
        float a4 = 0.f, a5 = 0.f, a6 = 0.f, a7 = 0.f;
        int tt = 0;
        for (; tt + 8 <= cn; tt += 8) {
            int   s0 = (int)__float_as_uint(sclds[r][512 + tt + 0]);
            int   s1 = (int)__float_as_uint(sclds[r][512 + tt + 1]);
            int   s2 = (int)__float_as_uint(sclds[r][512 + tt + 2]);
            int   s3 = (int)__float_as_uint(sclds[r][512 + tt + 3]);
            int   s4 = (int)__float_as_uint(sclds[r][512 + tt + 4]);
            int   s5 = (int)__float_as_uint(sclds[r][512 + tt + 5]);
            int   s6 = (int)__float_as_uint(sclds[r][512 + tt + 6]);
            int   s7 = (int)__float_as_uint(sclds[r][512 + tt + 7]);
            float w0 = sclds[r][tt + 0], w1 = sclds[r][tt + 1];
            float w2 = sclds[r][tt + 2], w3 = sclds[r][tt + 3];
            float w4 = sclds[r][tt + 4], w5 = sclds[r][tt + 5];
            float w6 = sclds[r][tt + 6], w7 = sclds[r][tt + 7];
            a0 = fmaf(w0, vb[(size_t)s0 * DM], a0);
            a1 = fmaf(w1, vb[(size_t)s1 * DM], a1);
            a2 = fmaf(w2, vb[(size_t)s2 * DM], a2);
            a3 = fmaf(w3, vb[(size_t)s3 * DM], a3);
            a4 = fmaf(w4, vb[(size_t)s4 * DM], a4);
            a5 = fmaf(w5, vb[(size_t)s5 * DM], a5);
            a6 = fmaf(w6, vb[(size_t)s6 * DM], a6);
            a7 = fmaf(w7, vb[(size_t)s7 * DM], a7);
        }
        for (; tt < cn; ++tt) {
            int s0 = (int)__float_as_uint(sclds[r][512 + tt]);
            a0 = fmaf(sclds[r][tt], vb[(size_t)s0 * DM], a0);
        }
        Oh[(size_t)(b * L + lbase + r) * DM + h * DH + lane] =
            (((a0 + a1) + (a2 + a3)) + ((a4 + a5) + (a6 + a7))) * inv;
    }
}

// ---------------------------------------------------------------------------
extern "C" void kernel_launch(void* const* d_in, const int* in_sizes, int n_in,
                              void* d_out, int out_size, void* d_ws, size_t ws_size,
                              hipStream_t stream)
{
    const float* q  = (const float*)d_in[0];
    const float* k  = (const float*)d_in[1];
    const float* v  = (const float*)d_in[2];
    const float* Wq = (const float*)d_in[3];
    const float* bq = (const float*)d_in[4];
    const float* Wk = (const float*)d_in[5];
    const float* bk = (const float*)d_in[6];
    const float* Wv = (const float*)d_in[7];
    const float* bv = (const float*)d_in[8];
    const float* Wo = (const float*)d_in[9];
    const float* bo = (const float*)d_in[10];
    // d_in[11] = pos_bias: per-head additive constant -> top-k/softmax invariant -> no-op.

    float* out = (float*)d_out;
    char*  ws  = (char*)d_ws;

    const size_t MB = 1024 * 1024;
    float*          Qp = (float*)(ws);                       //  0-8 MiB
    unsigned short* Kf = (unsigned short*)(ws + 8 * MB);     //  8-20 MiB (fragment-ordered)
    float*          Vp = (float*)(ws + 20 * MB);             // 20-36
    float*          Oh = (float*)(ws + 36 * MB);             // 36-52
    unsigned short* WvH = (unsigned short*)(ws + 36 * MB);   // overlaps Oh head (dead until attn)
    unsigned short* WvL = (unsigned short*)(ws + 38 * MB);
    unsigned short* WoH = (unsigned short*)(ws + 52 * MB);   // 52-54
    unsigned short* WoL = (unsigned short*)(ws + 54 * MB);   // 54-56

    const int M = B * L;  // 4096
    dim3 blk(256);

    transpose_split_dual<<<dim3(DM / 32, DM / 32, 2), blk, 0, stream>>>(
        Wv, WvH, WvL, Wo, WoH, WoL, DM, DM);

    gemm_mfma_split<<<dim3(DM / 128, M / 128), blk, 0, stream>>>(v, WvH, WvL, bv, Vp, M, DM, DM);

    qk_proj<<<dim3((H * R) / 128, M / 128, 2), blk, 0, stream>>>(
        q, Wq, bq, Qp, k, Wk, bk, Kf, M, H * R, DM);

    score_select_gather<<<dim3(4096), dim3(1024), 0, stream>>>(Qp, Kf, Vp, Oh);

    gemm_mfma_split<<<dim3(DM / 128, M / 128), blk, 0, stream>>>(Oh, WoH, WoL, bo, out, M, DM, DM);
}